// Round 9
// baseline (164.039 us; speedup 1.0000x reference)
//
#include <hip/hip_runtime.h>
#include <hip/hip_bf16.h>

#define K_DIM 1024
#define M_DIM 4096
#define N_DIM 8192
#define BK 32
#define BM 128
#define BN 128
#define NT 32                    // 1024 / 32 K-tiles

#define OFF_A 0                  // bytes within one buffer
#define OFF_B 8192
#define OFF_P 16384
#define BUF_BYTES 24576          // A 8K + B 8K + P 8K

typedef __attribute__((ext_vector_type(8))) __bf16 bf16x8_t;
typedef __attribute__((ext_vector_type(4))) float f32x4;

#define SBAR __builtin_amdgcn_s_barrier()
#define VMCNT0 asm volatile("s_waitcnt vmcnt(0)" ::: "memory")

__device__ inline unsigned short f2bf(float f) {
    unsigned u = __float_as_uint(f);
    u += 0x7FFF + ((u >> 16) & 1);   // round-to-nearest-even
    return (unsigned short)(u >> 16);
}

__device__ __forceinline__ void gload_lds16(const void* g, void* l) {
    __builtin_amdgcn_global_load_lds(
        (const __attribute__((address_space(1))) unsigned int*)g,
        (__attribute__((address_space(3))) unsigned int*)l, 16, 0, 0);
}

// softmax over 1024 cols for wa (blocks 0..4095) and wb (blocks 4096..8191)
__global__ void dual_softmax_kernel(const float* __restrict__ wa,
                                    const float* __restrict__ wb,
                                    unsigned short* __restrict__ pa,
                                    unsigned short* __restrict__ pb) {
    const int idx = blockIdx.x;
    const float* w = (idx < M_DIM) ? wa : wb;
    unsigned short* o = (idx < M_DIM) ? pa : pb;
    const int row = idx & (M_DIM - 1);
    const int tid = threadIdx.x;
    const float4 v = reinterpret_cast<const float4*>(w + (size_t)row * K_DIM)[tid];
    float m = fmaxf(fmaxf(v.x, v.y), fmaxf(v.z, v.w));
    #pragma unroll
    for (int off = 32; off >= 1; off >>= 1) m = fmaxf(m, __shfl_xor(m, off));
    __shared__ float redm[4];
    __shared__ float reds[4];
    if ((tid & 63) == 0) redm[tid >> 6] = m;
    __syncthreads();
    m = fmaxf(fmaxf(redm[0], redm[1]), fmaxf(redm[2], redm[3]));
    const float e0 = __expf(v.x - m), e1 = __expf(v.y - m);
    const float e2 = __expf(v.z - m), e3 = __expf(v.w - m);
    float s = e0 + e1 + e2 + e3;
    #pragma unroll
    for (int off = 32; off >= 1; off >>= 1) s += __shfl_xor(s, off);
    if ((tid & 63) == 0) reds[tid >> 6] = s;
    __syncthreads();
    s = reds[0] + reds[1] + reds[2] + reds[3];
    const float inv = 1.0f / s;
    ushort4 r;
    r.x = f2bf(e0 * inv); r.y = f2bf(e1 * inv);
    r.z = f2bf(e2 * inv); r.w = f2bf(e3 * inv);
    reinterpret_cast<ushort4*>(o + (size_t)row * K_DIM)[tid] = r;
}

// prev (K x N, f32) -> prevT (N x K, bf16)
__global__ void transpose_conv_kernel(const float* __restrict__ src,
                                      unsigned short* __restrict__ dst) {
    __shared__ float t[32][33];
    const int n0 = blockIdx.x * 32;
    const int k0 = blockIdx.y * 32;
    const int tx = threadIdx.x, ty = threadIdx.y;   // 32 x 8
    #pragma unroll
    for (int i = ty; i < 32; i += 8)
        t[i][tx] = src[(size_t)(k0 + i) * N_DIM + n0 + tx];
    __syncthreads();
    #pragma unroll
    for (int i = ty; i < 32; i += 8)
        dst[(size_t)(n0 + i) * K_DIM + k0 + tx] = f2bf(t[tx][i]);
}

__global__ void coef_kernel(const float* __restrict__ tw,
                            float4* __restrict__ coef) {
    const int r = blockIdx.x * 256 + threadIdx.x;
    float p[16];
    float m = -1e30f;
    #pragma unroll
    for (int k = 0; k < 16; ++k) { p[k] = tw[k * M_DIM + r]; m = fmaxf(m, p[k]); }
    float s = 0.f;
    #pragma unroll
    for (int k = 0; k < 16; ++k) { p[k] = __expf(p[k] - m); s += p[k]; }
    const float inv = 1.f / s;
    #pragma unroll
    for (int k = 0; k < 16; ++k) p[k] *= inv;
    const float cA  = p[2]+p[3]+p[6]+p[7]-p[8]-p[9]-p[12]-p[13];
    const float cB  = p[4]+p[5]+p[6]+p[7]-p[8]-p[9]-p[10]-p[11];
    const float cAB = p[1]-p[2]-p[4]-2.f*p[6]-p[7]+p[8]+2.f*p[9]+p[11]+p[13]-p[14];
    const float c0  = p[8]+p[9]+p[10]+p[11]+p[12]+p[13]+p[14]+p[15];
    coef[r] = make_float4(cA, cB, cAB, c0);
}

// Fused dual GEMM. 128x128 tile, 4 waves (2x2, 64x64 each), 16x16x32 MFMA,
// BK=32, double-buffered LDS (48 KB) -> 2 blocks/CU co-resident (the m114
// overlap that made R2 the best point so far), with depth-1 staging prefetch:
//   tile t: STAGE(t+1 -> other buf); READ 12 frags(t); MFMA x32;
//           vmcnt(0) [cover = full tile ~1400 cy]; s_barrier.
// One barrier + one cover-protected drain per tile (R2 had a zero-cover
// drain; R3-R8's 1-block/CU lockstep schedules all ran LDS+MFMA as a sum).
// Swizzle (64-B rows, verified 0 conflicts in R7):
//   LDS(row,c16) = G(row, c16 ^ ((row>>1)&3)); reads apply the same XOR.
__global__ __launch_bounds__(256, 2)
void dual_gemm_kernel(const unsigned short* __restrict__ pa,
                      const unsigned short* __restrict__ pb,
                      const unsigned short* __restrict__ pv,
                      const float4* __restrict__ coef,
                      float* __restrict__ out) {
    __shared__ unsigned short lds[2 * BUF_BYTES / 2];   // 48 KB

    const int tid = threadIdx.x;
    const int lane = tid & 63;
    const int w = tid >> 6;            // 0..3
    const int wm = w >> 1, wn = w & 1; // 2x2 wave grid, 64x64 each
    const int bm = blockIdx.y, bn = blockIdx.x;

    // staging: chunk = 16 rows x 64 B = 1024 B; 8 chunks/operand; wave owns 2.
    // lane l -> row = chunk*16 + (l>>2), lds col16 = l&3,
    // src col16 = (l&3) ^ ((l>>3)&3)  ( == (l&3) ^ ((row>>1)&3) ).
    const int sub  = lane >> 2;                    // 0..15
    const int scol = (lane & 3) ^ ((lane >> 3) & 3);

    const int c0 = 2 * w, c1 = 2 * w + 1;          // this wave's chunks
    const char* sA0 = (const char*)pa + ((size_t)(bm * BM + c0 * 16 + sub) * K_DIM) * 2 + scol * 16;
    const char* sA1 = (const char*)pa + ((size_t)(bm * BM + c1 * 16 + sub) * K_DIM) * 2 + scol * 16;
    const char* sB0 = (const char*)pb + ((size_t)(bm * BM + c0 * 16 + sub) * K_DIM) * 2 + scol * 16;
    const char* sB1 = (const char*)pb + ((size_t)(bm * BM + c1 * 16 + sub) * K_DIM) * 2 + scol * 16;
    const char* sP0 = (const char*)pv + ((size_t)(bn * BN + c0 * 16 + sub) * K_DIM) * 2 + scol * 16;
    const char* sP1 = (const char*)pv + ((size_t)(bn * BN + c1 * 16 + sub) * K_DIM) * 2 + scol * 16;

    const int fr = lane & 15;
    const int fk = lane >> 4;          // 0..3 (16B col slot in 64-B row)

    // precompute the 12 frag byte-offsets (loop-invariant)
    int aoff[4], poff[4];
    #pragma unroll
    for (int i = 0; i < 4; ++i) {
        const int ar = wm * 64 + fr + i * 16;
        aoff[i] = ar * 64 + ((fk ^ ((ar >> 1) & 3)) << 4);
        const int pr = wn * 64 + fr + i * 16;
        poff[i] = pr * 64 + ((fk ^ ((pr >> 1) & 3)) << 4);
    }

    f32x4 accA[4][4], accB[4][4];
    const f32x4 z = {0.f, 0.f, 0.f, 0.f};
    #pragma unroll
    for (int i = 0; i < 4; ++i)
        #pragma unroll
        for (int j = 0; j < 4; ++j) { accA[i][j] = z; accB[i][j] = z; }

    #define STAGE_TO(buf_base) do {                                          \
        char* base = (char*)(buf_base);                                      \
        gload_lds16(sA0, base + OFF_A + c0 * 1024);                          \
        gload_lds16(sA1, base + OFF_A + c1 * 1024);                          \
        gload_lds16(sB0, base + OFF_B + c0 * 1024);                          \
        gload_lds16(sB1, base + OFF_B + c1 * 1024);                          \
        gload_lds16(sP0, base + OFF_P + c0 * 1024);                          \
        gload_lds16(sP1, base + OFF_P + c1 * 1024);                          \
        sA0 += BK * 2; sA1 += BK * 2; sB0 += BK * 2; sB1 += BK * 2;          \
        sP0 += BK * 2; sP1 += BK * 2;                                        \
    } while (0)

    char* buf0 = (char*)lds;
    char* buf1 = (char*)lds + BUF_BYTES;

    // prologue: stage tile 0 into buf0 (one-time zero-cover drain)
    STAGE_TO(buf0);
    VMCNT0;
    SBAR;

    for (int t = 0; t < NT; ++t) {
        const bool more = (t < NT - 1);
        if (more) STAGE_TO(buf1);               // tile t+1, 6 loads in flight

        bf16x8_t af[4], bfv[4], pf[4];
        #pragma unroll
        for (int i = 0; i < 4; ++i) {
            af[i]  = *reinterpret_cast<const bf16x8_t*>(buf0 + OFF_A + aoff[i]);
            bfv[i] = *reinterpret_cast<const bf16x8_t*>(buf0 + OFF_B + aoff[i]);
            pf[i]  = *reinterpret_cast<const bf16x8_t*>(buf0 + OFF_P + poff[i]);
        }

        __builtin_amdgcn_s_setprio(1);
        #pragma unroll
        for (int mi = 0; mi < 4; ++mi)
            #pragma unroll
            for (int ni = 0; ni < 4; ++ni) {
                accA[mi][ni] = __builtin_amdgcn_mfma_f32_16x16x32_bf16(
                    af[mi], pf[ni], accA[mi][ni], 0, 0, 0);
                accB[mi][ni] = __builtin_amdgcn_mfma_f32_16x16x32_bf16(
                    bfv[mi], pf[ni], accB[mi][ni], 0, 0, 0);
            }
        __builtin_amdgcn_s_setprio(0);

        if (more) {
            VMCNT0;                             // t+1 landed (full-tile cover)
            SBAR;                               // visible; buf0 free for t+2
        }
        char* tmp = buf0; buf0 = buf1; buf1 = tmp;
    }

    // epilogue: D layout col=lane&15, row=(lane>>4)*4+reg
    const int row_grp = lane >> 4;
    #pragma unroll
    for (int mi = 0; mi < 4; ++mi) {
        #pragma unroll
        for (int ni = 0; ni < 4; ++ni) {
            const int gr0 = bm * BM + wm * 64 + mi * 16 + row_grp * 4;
            const int gc  = bn * BN + wn * 64 + ni * 16 + (lane & 15);
            #pragma unroll
            for (int i = 0; i < 4; ++i) {
                const int r = gr0 + i;
                const float4 cf = coef[r];
                const float av = accA[mi][ni][i];
                const float bv = accB[mi][ni][i];
                out[(size_t)r * N_DIM + gc] =
                    fmaf(cf.z, av * bv, fmaf(cf.x, av, fmaf(cf.y, bv, cf.w)));
            }
        }
    }
}

extern "C" void kernel_launch(void* const* d_in, const int* in_sizes, int n_in,
                              void* d_out, int out_size, void* d_ws, size_t ws_size,
                              hipStream_t stream) {
    const float* prev = (const float*)d_in[0];   // (1024, 8192)
    const float* wa   = (const float*)d_in[1];   // (4096, 1024)
    const float* wb   = (const float*)d_in[2];   // (4096, 1024)
    const float* tw   = (const float*)d_in[3];   // (16, 4096)
    float* out = (float*)d_out;                  // (4096, 8192)

    char* ws = (char*)d_ws;
    unsigned short* pa = (unsigned short*)ws;                        // 8 MB
    unsigned short* pb = (unsigned short*)(ws + 8388608);            // 8 MB
    unsigned short* pv = (unsigned short*)(ws + 16777216);           // 16 MB
    float4* coef       = (float4*)(ws + 33554432);                   // 64 KB

    dual_softmax_kernel<<<2 * M_DIM, 256, 0, stream>>>(wa, wb, pa, pb);
    transpose_conv_kernel<<<dim3(N_DIM / 32, K_DIM / 32), dim3(32, 8), 0, stream>>>(prev, pv);
    coef_kernel<<<M_DIM / 256, 256, 0, stream>>>(tw, coef);
    dual_gemm_kernel<<<dim3(N_DIM / BN, M_DIM / BM), 256, 0, stream>>>(pa, pb, pv, coef, out);
}